// Round 3
// baseline (745.010 us; speedup 1.0000x reference)
//
#include <hip/hip_runtime.h>
#include <hip/hip_bf16.h>
#include <cstdint>
#include <cstddef>

#define T_TOK 4096
#define D_DIM 1024
#define E_NUM 8
#define F_DIM 4096

typedef __bf16 bf16_t;
typedef bf16_t bf16x8 __attribute__((ext_vector_type(8)));
typedef bf16_t bf16x4 __attribute__((ext_vector_type(4)));
typedef float f32x4 __attribute__((ext_vector_type(4)));

// async 16B global->LDS. LDS dest is wave-uniform base; HW adds lane*16.
__device__ __forceinline__ void gl_lds16(const void* g, void* l) {
    __builtin_amdgcn_global_load_lds(
        (const __attribute__((address_space(1))) unsigned int*)g,
        (__attribute__((address_space(3))) unsigned int*)l,
        16, 0, 0);
}

// ================= FAST-PATH workspace layout (bytes) =================
// w1t : bf16 image [e][nt=32][ks=16][n=128][kc=8][8]    = 64 MiB
// w2t : bf16 image [e][nt=8][ks=64][n=128][kc=8][8]     = 64 MiB
// h_t : bf16 image [rowblk<=71][fslab=64][row=128][128B]= 72 MiB
// x_bf: bf16 [4096][1024]                               = 8 MiB
// rowv: bf16 [8192][1024]                               = 16 MiB
#define F_W1T    0ull
#define F_W2T    67108864ull
#define F_HT     134217728ull
#define F_XBF    209715200ull
#define F_ROWV   218103808ull
#define F_SCORES 251658240ull
#define F_TOK    (F_SCORES + 131072ull)
#define F_SC     (F_TOK    + 131072ull)
#define F_T2R    (F_SC     + 131072ull)
#define F_CNT    (F_T2R    + 32768ull)
#define F_OFF    (F_CNT    + 32ull)
#define F_BLK    (F_OFF    + 32ull)
#define FAST_NEED (F_BLK + 32ull)

// ================= FALLBACK (round-1) workspace layout =================
#define WS_H      0ull
#define WS_ROWV   (WS_H      + 8192ull*4096*2)
#define WS_SCORES (WS_ROWV   + 8192ull*1024*4)
#define WS_TOK    (WS_SCORES + 4096ull*8*4)
#define WS_SC     (WS_TOK    + 8ull*4096*4)
#define WS_T2R    (WS_SC     + 8ull*4096*4)
#define WS_CNT    (WS_T2R    + 4096ull*2*4)
#define WS_OFF    (WS_CNT    + 32ull)
#define WS_BLK    (WS_OFF    + 32ull)

// ---------------- router body (device fn, used by mega + fallback) -----
__device__ __forceinline__ void router_body(
    int t, int lane,
    const float* __restrict__ x, const float* __restrict__ noise,
    const float* __restrict__ gate_w, const float* __restrict__ gate_b,
    const float* __restrict__ noise_w, const float* __restrict__ noise_b,
    float* __restrict__ scores, int* __restrict__ tok_tmp,
    float* __restrict__ sc_tmp, int* __restrict__ tok2row, int* __restrict__ counts)
{
    const float* xr = x + (size_t)t * D_DIM;
    float acc[8] = {0,0,0,0,0,0,0,0};
    for (int d = lane; d < D_DIM; d += 64) {
        float xv = xr[d];
#pragma unroll
        for (int e = 0; e < 8; e++)
            acc[e] += xv * (gate_w[d*8+e] + noise_w[d*8+e]);
    }
#pragma unroll
    for (int e = 0; e < 8; e++) {
#pragma unroll
        for (int m = 1; m < 64; m <<= 1)
            acc[e] += __shfl_xor(acc[e], m);
    }
    float lg[8];
#pragma unroll
    for (int e = 0; e < 8; e++)
        lg[e] = acc[e] + gate_b[e] + noise_b[e] + noise[t*8+e];
    int e1 = 0; float v1 = lg[0];
#pragma unroll
    for (int e = 1; e < 8; e++) if (lg[e] > v1) { v1 = lg[e]; e1 = e; }
    int e2 = -1; float v2 = -INFINITY;
#pragma unroll
    for (int e = 0; e < 8; e++) if (e != e1 && lg[e] > v2) { v2 = lg[e]; e2 = e; }
    float ex = expf(v2 - v1);
    float den = 1.0f + ex;
    float s1 = 1.0f / den, s2 = ex / den;
    if (lane < 8)
        scores[t*8+lane] = (lane==e1) ? s1 : ((lane==e2) ? s2 : 0.0f);
    if (lane == 0) {
        int p1 = atomicAdd(&counts[e1], 1);
        tok_tmp[e1*T_TOK + p1] = t; sc_tmp[e1*T_TOK + p1] = s1;
        tok2row[t*2]   = (e1<<16) | p1;
        int p2 = atomicAdd(&counts[e2], 1);
        tok_tmp[e2*T_TOK + p2] = t; sc_tmp[e2*T_TOK + p2] = s2;
        tok2row[t*2+1] = (e2<<16) | p2;
    }
}

// ---------------- mega prep: weight transpose + x cvt + router --------
// grid: [0,4096) w1 tiles, [4096,8192) w2 tiles, [8192,10240) x cvt,
//       [10240,11264) router
__global__ __launch_bounds__(256) void mega_prep_k(
    const float* __restrict__ x, const float* __restrict__ noise,
    const float* __restrict__ gate_w, const float* __restrict__ gate_b,
    const float* __restrict__ noise_w, const float* __restrict__ noise_b,
    const float* __restrict__ w1, const float* __restrict__ w2,
    bf16_t* __restrict__ w1t, bf16_t* __restrict__ w2t, bf16_t* __restrict__ xb,
    float* __restrict__ scores, int* __restrict__ tok_tmp,
    float* __restrict__ sc_tmp, int* __restrict__ tok2row, int* __restrict__ counts)
{
    __shared__ alignas(16) float ftile[64 * 129];   // 33024 B
    int b = blockIdx.x, tid = threadIdx.x;
    if (b < 8192) {
        // weight tile transpose: read 64k x 128n f32 coalesced, emit bf16 image
        const float* src; bf16_t* dst; int Ndim;
        if (b < 4096) {
            int ks = b & 15, ntile = (b >> 4) & 31, e = b >> 9;
            src = w1 + ((size_t)e * D_DIM + ks * 64) * F_DIM + ntile * 128;
            Ndim = F_DIM;
            dst = w1t + (((size_t)(e * 32 + ntile) * 16) + ks) * 8192;
        } else {
            int b2 = b - 4096;
            int ks = b2 & 63, ntile = (b2 >> 6) & 7, e = b2 >> 9;
            src = w2 + ((size_t)e * F_DIM + ks * 64) * D_DIM + ntile * 128;
            Ndim = D_DIM;
            dst = w2t + (((size_t)(e * 8 + ntile) * 64) + ks) * 8192;
        }
        int c0 = (tid & 31) * 4, r0 = tid >> 5;
#pragma unroll
        for (int i = 0; i < 8; i++) {
            int r = r0 + i * 8;
            f32x4 v = *(const f32x4*)(src + (size_t)r * Ndim + c0);
#pragma unroll
            for (int j = 0; j < 4; j++)
                ftile[r * 129 + c0 + j] = v[j];
        }
        __syncthreads();
#pragma unroll
        for (int i = 0; i < 4; i++) {
            int q = tid + i * 256;            // output 16B chunk id
            int n = q >> 3, p = q & 7;
            int c = p ^ (n & 7);              // logical k-chunk (swizzle baked)
            union { bf16_t u[8]; bf16x8 v; } pk;
#pragma unroll
            for (int jj = 0; jj < 8; jj++)
                pk.u[jj] = (bf16_t)ftile[(c * 8 + jj) * 129 + n];
            *(bf16x8*)(dst + (size_t)q * 8) = pk.v;
        }
    } else if (b < 10240) {
        size_t i = ((size_t)(b - 8192) * 256 + tid) * 8;
        f32x4 a = *(const f32x4*)(x + i);
        f32x4 c = *(const f32x4*)(x + i + 4);
        union { bf16_t u[8]; bf16x8 v; } pk;
#pragma unroll
        for (int j = 0; j < 4; j++) { pk.u[j] = (bf16_t)a[j]; pk.u[4+j] = (bf16_t)c[j]; }
        *(bf16x8*)(xb + i) = pk.v;
    } else {
        int t = (b - 10240) * 4 + (tid >> 6);
        router_body(t, tid & 63, x, noise, gate_w, gate_b, noise_w, noise_b,
                    scores, tok_tmp, sc_tmp, tok2row, counts);
    }
}

__global__ void prefix_k(const int* __restrict__ counts, int* __restrict__ offsets,
                         int* __restrict__ blk_off) {
    if (threadIdx.x == 0) {
        int o = 0, bb = 0;
        for (int e = 0; e < 8; e++) {
            offsets[e] = o; blk_off[e] = bb;
            o += counts[e]; bb += (counts[e] + 127) >> 7;
        }
    }
}

__global__ __launch_bounds__(256) void aux_k(const float* __restrict__ scores,
                                             float* __restrict__ out_aux) {
    __shared__ float part[256];
    int i = threadIdx.x;
    int e = i & 7, g = i >> 3;
    float s = 0.f;
    for (int t = g; t < T_TOK; t += 32) s += scores[t*8+e];
    part[i] = s; __syncthreads();
    for (int st = 128; st >= 8; st >>= 1) {
        if (i < st) part[i] += part[i+st];
        __syncthreads();
    }
    if (i == 0) {
        float aux = 0.f;
        for (int ee = 0; ee < 8; ee++) {
            float imp = part[ee] * (1.0f / (float)T_TOK);
            aux += 0.125f * (logf(0.125f) - logf(imp + 1e-8f));
        }
        *out_aux = aux;
    }
}

// ---------------- ffn1: h_t = silu(x @ w1 + b1), BK=64 ----------------
__global__ __launch_bounds__(256) void ffn1_v3_k(
    const bf16_t* __restrict__ xb, const bf16_t* __restrict__ w1t,
    const float* __restrict__ b1, const int* __restrict__ tok_tmp,
    const int* __restrict__ counts, const int* __restrict__ blk_off,
    char* __restrict__ h_t)
{
    int bx = blockIdx.x;
    int nt = bx & 31, mt = (bx >> 5) & 31, e = bx >> 10;
    int ne = counts[e];
    if (mt * 128 >= ne) return;

    __shared__ alignas(16) char smem[32768];   // A 16K | B 16K ; epilogue aliases
    int tid = threadIdx.x, w = tid >> 6, l = tid & 63;
    int lc = (l & 7) ^ ((l >> 3) & 7);         // logical k-chunk for staging lane

    const char* gA[4];
#pragma unroll
    for (int j = 0; j < 4; j++) {
        int row = mt * 128 + w * 32 + j * 8 + (l >> 3);
        int tok = tok_tmp[e * T_TOK + (row < ne ? row : 0)];
        gA[j] = (const char*)xb + (size_t)tok * 2048 + lc * 16;
    }
    const char* gB = (const char*)w1t + (size_t)(e * 32 + nt) * 262144 + w * 4096 + l * 16;
    char* lA = smem + w * 4096;
    char* lB = smem + 16384 + w * 4096;

    int fr = l & 15, kq = l >> 4;
    int wm = (w & 1) * 64, wn = (w >> 1) * 64;
    int aoff[4][2], boff[4][2];
#pragma unroll
    for (int i = 0; i < 4; i++)
#pragma unroll
        for (int c2 = 0; c2 < 2; c2++) {
            int ra = wm + i * 16 + fr;
            aoff[i][c2] = ra * 128 + (((c2 * 4 + kq) ^ (ra & 7)) << 4);
            int rb = wn + i * 16 + fr;
            boff[i][c2] = 16384 + rb * 128 + (((c2 * 4 + kq) ^ (rb & 7)) << 4);
        }

    f32x4 acc[4][4] = {};
    for (int ks = 0; ks < 16; ks++) {
#pragma unroll
        for (int j = 0; j < 4; j++) {
            gl_lds16(gA[j], lA + j * 1024);
            gl_lds16(gB + j * 1024, lB + j * 1024);
        }
        gB += 16384;
#pragma unroll
        for (int j = 0; j < 4; j++) gA[j] += 128;
        __syncthreads();
        bf16x8 af[2][4], bf[2][4];
#pragma unroll
        for (int c2 = 0; c2 < 2; c2++)
#pragma unroll
            for (int i = 0; i < 4; i++) {
                af[c2][i] = *(const bf16x8*)(smem + aoff[i][c2]);
                bf[c2][i] = *(const bf16x8*)(smem + boff[i][c2]);
            }
#pragma unroll
        for (int c2 = 0; c2 < 2; c2++)
#pragma unroll
            for (int mi = 0; mi < 4; mi++)
#pragma unroll
                for (int ni = 0; ni < 4; ni++)
                    acc[mi][ni] = __builtin_amdgcn_mfma_f32_16x16x32_bf16(
                        af[c2][mi], bf[c2][ni], acc[mi][ni], 0, 0, 0);
        __syncthreads();
    }

    // epilogue: +b1, silu, build 2 fslab images (each [128 rows][8 chunks][16B]) in LDS
    const float* b1e = b1 + (size_t)e * F_DIM + nt * 128;
#pragma unroll
    for (int mi = 0; mi < 4; mi++)
#pragma unroll
        for (int ni = 0; ni < 4; ni++) {
            int col = wn + ni * 16 + fr;
            float bb = b1e[col];
#pragma unroll
            for (int r = 0; r < 4; r++) {
                int row = wm + mi * 16 + kq * 4 + r;
                float v = acc[mi][ni][r] + bb;
                v = v / (1.0f + expf(-v));
                int off = (col >> 6) * 16384 + row * 128
                        + ((((col & 63) >> 3) ^ (row & 7)) << 4) + ((col & 7) << 1);
                *(bf16_t*)(smem + off) = (bf16_t)v;
            }
        }
    __syncthreads();
    {
        char* dst = h_t + (size_t)(blk_off[e] + mt) * 1048576ull
                  + (size_t)nt * 32768 + tid * 16;
        const char* src = smem + tid * 16;
#pragma unroll
        for (int i = 0; i < 8; i++)
            *(f32x4*)(dst + i * 4096) = *(const f32x4*)(src + i * 4096);
    }
}

// ---------------- ffn2: rowv(bf16) = score*(h @ w2 + b2), BK=64 -------
__global__ __launch_bounds__(256) void ffn2_v3_k(
    const char* __restrict__ h_t, const bf16_t* __restrict__ w2t,
    const float* __restrict__ b2, const float* __restrict__ sc_tmp,
    const int* __restrict__ counts, const int* __restrict__ offsets,
    const int* __restrict__ blk_off, bf16_t* __restrict__ rowv)
{
    int bx = blockIdx.x;
    int nt = bx & 7, mt = (bx >> 3) & 31, e = bx >> 8;
    int ne = counts[e];
    if (mt * 128 >= ne) return;

    __shared__ alignas(16) char smem[35328];   // stage 32K | rowsc @34816
    float* rowsc = (float*)(smem + 34816);
    int tid = threadIdx.x, w = tid >> 6, l = tid & 63;
    if (tid < 128) {
        int r = mt * 128 + tid;
        rowsc[tid] = (r < ne) ? sc_tmp[e * T_TOK + r] : 0.0f;
    }

    const char* gA = h_t + (size_t)(blk_off[e] + mt) * 1048576ull + w * 4096 + l * 16;
    const char* gB = (const char*)w2t + (size_t)(e * 8 + nt) * 1048576ull + w * 4096 + l * 16;
    char* lA = smem + w * 4096;
    char* lB = smem + 16384 + w * 4096;

    int fr = l & 15, kq = l >> 4;
    int wm = (w & 1) * 64, wn = (w >> 1) * 64;
    int aoff[4][2], boff[4][2];
#pragma unroll
    for (int i = 0; i < 4; i++)
#pragma unroll
        for (int c2 = 0; c2 < 2; c2++) {
            int ra = wm + i * 16 + fr;
            aoff[i][c2] = ra * 128 + (((c2 * 4 + kq) ^ (ra & 7)) << 4);
            int rb = wn + i * 16 + fr;
            boff[i][c2] = 16384 + rb * 128 + (((c2 * 4 + kq) ^ (rb & 7)) << 4);
        }

    f32x4 acc[4][4] = {};
    for (int ks = 0; ks < 64; ks++) {
#pragma unroll
        for (int j = 0; j < 4; j++) {
            gl_lds16(gA + j * 1024, lA + j * 1024);
            gl_lds16(gB + j * 1024, lB + j * 1024);
        }
        gA += 16384; gB += 16384;
        __syncthreads();
        bf16x8 af[2][4], bf[2][4];
#pragma unroll
        for (int c2 = 0; c2 < 2; c2++)
#pragma unroll
            for (int i = 0; i < 4; i++) {
                af[c2][i] = *(const bf16x8*)(smem + aoff[i][c2]);
                bf[c2][i] = *(const bf16x8*)(smem + boff[i][c2]);
            }
#pragma unroll
        for (int c2 = 0; c2 < 2; c2++)
#pragma unroll
            for (int mi = 0; mi < 4; mi++)
#pragma unroll
                for (int ni = 0; ni < 4; ni++)
                    acc[mi][ni] = __builtin_amdgcn_mfma_f32_16x16x32_bf16(
                        af[c2][mi], bf[c2][ni], acc[mi][ni], 0, 0, 0);
        __syncthreads();
    }

    // epilogue: +b2, *score, bf16 tile in LDS (stride 272B), coalesced row dump
    const float* b2e = b2 + (size_t)e * D_DIM + nt * 128;
#pragma unroll
    for (int mi = 0; mi < 4; mi++)
#pragma unroll
        for (int ni = 0; ni < 4; ni++) {
            int col = wn + ni * 16 + fr;
            float bb = b2e[col];
#pragma unroll
            for (int r = 0; r < 4; r++) {
                int row = wm + mi * 16 + kq * 4 + r;
                float v = (acc[mi][ni][r] + bb) * rowsc[row];
                *(bf16_t*)(smem + row * 272 + col * 2) = (bf16_t)v;
            }
        }
    __syncthreads();
    {
        int row = tid >> 1, half = tid & 1;
        if (mt * 128 + row < ne) {
            char* dst = (char*)rowv + (size_t)(offsets[e] + mt * 128 + row) * 2048
                      + nt * 256 + half * 128;
            const char* src = smem + row * 272 + half * 128;
#pragma unroll
            for (int j = 0; j < 8; j++)
                *(f32x4*)(dst + j * 16) = *(const f32x4*)(src + j * 16);
        }
    }
}

// ---------------- combine: out[t] = rowv[r0] + rowv[r1] (bf16 in) -----
__global__ __launch_bounds__(256) void combine_v3_k(
    const bf16_t* __restrict__ rowv, const int* __restrict__ tok2row,
    const int* __restrict__ offsets, float* __restrict__ out)
{
    int t = blockIdx.x;
    int p0 = tok2row[t*2], p1 = tok2row[t*2+1];
    int r0 = offsets[p0 >> 16] + (p0 & 0xffff);
    int r1 = offsets[p1 >> 16] + (p1 & 0xffff);
    int d = threadIdx.x * 4;
    bf16x4 a = *(const bf16x4*)(rowv + (size_t)r0 * D_DIM + d);
    bf16x4 b = *(const bf16x4*)(rowv + (size_t)r1 * D_DIM + d);
    f32x4 o;
#pragma unroll
    for (int j = 0; j < 4; j++) o[j] = (float)a[j] + (float)b[j];
    *(f32x4*)(out + (size_t)t * D_DIM + d) = o;
}

// ======================= FALLBACK (round-1 path) =======================
#define BM 128
#define BN 128
#define BK 32
#define LDA 40
#define LDCB 136
#define LDCF 68
#define SMEM_BYTES 35328

__global__ __launch_bounds__(256) void router_fb_k(
    const float* __restrict__ x, const float* __restrict__ noise,
    const float* __restrict__ gate_w, const float* __restrict__ gate_b,
    const float* __restrict__ noise_w, const float* __restrict__ noise_b,
    float* __restrict__ scores, int* __restrict__ tok_tmp,
    float* __restrict__ sc_tmp, int* __restrict__ tok2row, int* __restrict__ counts)
{
    int t = blockIdx.x * 4 + (threadIdx.x >> 6);
    router_body(t, threadIdx.x & 63, x, noise, gate_w, gate_b, noise_w, noise_b,
                scores, tok_tmp, sc_tmp, tok2row, counts);
}

__global__ __launch_bounds__(256) void ffn1_fb_k(
    const float* __restrict__ x, const float* __restrict__ w1, const float* __restrict__ b1,
    const int* __restrict__ tok_tmp, const int* __restrict__ counts,
    const int* __restrict__ offsets, bf16_t* __restrict__ h)
{
    int e  = blockIdx.x >> 5;
    int mt = blockIdx.x & 31;
    int nt = blockIdx.y;
    int ne = counts[e];
    if (mt * BM >= ne) return;
    int nb = nt * BN;
    const float* W = w1 + (size_t)e * D_DIM * F_DIM;

    __shared__ alignas(16) char smem[SMEM_BYTES];
    bf16_t* As = (bf16_t*)smem;
    bf16_t* Bs = (bf16_t*)(smem + 10240);
    int* rowtok = (int*)(smem + 34816);

    int tid = threadIdx.x;
    if (tid < 128) {
        int r = mt*BM + tid;
        rowtok[tid] = (r < ne) ? tok_tmp[e*T_TOK + r] : -1;
    }
    __syncthreads();

    f32x4 acc[4][4] = {};
    int wave = tid >> 6, lane = tid & 63;
    int wm = (wave & 1) * 64, wn = (wave >> 1) * 64;
    int fr = lane & 15, fk = (lane >> 4) * 8;
    int sr = tid >> 1, sh = (tid & 1) * 16;
    int bn_ = tid & 127, bk_ = (tid >> 7) * 16;

    for (int k0 = 0; k0 < D_DIM; k0 += BK) {
        {
            int tok = rowtok[sr];
            union { bf16_t u[16]; bf16x8 v[2]; } pk;
            if (tok >= 0) {
                const float* src = x + (size_t)tok * D_DIM + k0 + sh;
#pragma unroll
                for (int j = 0; j < 16; j++) pk.u[j] = (bf16_t)src[j];
            } else {
#pragma unroll
                for (int j = 0; j < 16; j++) pk.u[j] = (bf16_t)0.0f;
            }
            *(bf16x8*)(As + sr*LDA + sh)     = pk.v[0];
            *(bf16x8*)(As + sr*LDA + sh + 8) = pk.v[1];
        }
        {
            union { bf16_t u[16]; bf16x8 v[2]; } pk;
            const float* src = W + (size_t)(k0 + bk_) * F_DIM + nb + bn_;
#pragma unroll
            for (int j = 0; j < 16; j++) pk.u[j] = (bf16_t)src[(size_t)j * F_DIM];
            *(bf16x8*)(Bs + bn_*LDA + bk_)     = pk.v[0];
            *(bf16x8*)(Bs + bn_*LDA + bk_ + 8) = pk.v[1];
        }
        __syncthreads();
        bf16x8 af[4], bfr[4];
#pragma unroll
        for (int i = 0; i < 4; i++) af[i]  = *(bf16x8*)(As + (wm + i*16 + fr)*LDA + fk);
#pragma unroll
        for (int i = 0; i < 4; i++) bfr[i] = *(bf16x8*)(Bs + (wn + i*16 + fr)*LDA + fk);
#pragma unroll
        for (int mi = 0; mi < 4; mi++)
#pragma unroll
            for (int ni = 0; ni < 4; ni++)
                acc[mi][ni] = __builtin_amdgcn_mfma_f32_16x16x32_bf16(af[mi], bfr[ni], acc[mi][ni], 0, 0, 0);
        __syncthreads();
    }

    bf16_t* Ct = (bf16_t*)smem;
    const float* b1e = b1 + (size_t)e * F_DIM + nb;
#pragma unroll
    for (int mi = 0; mi < 4; mi++) {
        int row = wm + mi*16 + ((lane >> 4) << 2);
#pragma unroll
        for (int ni = 0; ni < 4; ni++) {
            int col = wn + ni*16 + fr;
            float bb = b1e[col];
#pragma unroll
            for (int r = 0; r < 4; r++) {
                float v = acc[mi][ni][r] + bb;
                float sv = v / (1.0f + expf(-v));
                Ct[(row + r)*LDCB + col] = (bf16_t)sv;
            }
        }
    }
    __syncthreads();
    {
        int row = tid >> 1, seg = (tid & 1) * 64;
        if (mt*BM + row < ne) {
            int grow = offsets[e] + mt*BM + row;
            bf16_t* dst = h + (size_t)grow * F_DIM + nb + seg;
#pragma unroll
            for (int j = 0; j < 8; j++)
                *(bf16x8*)(dst + j*8) = *(bf16x8*)(Ct + row*LDCB + seg + j*8);
        }
    }
}

__global__ __launch_bounds__(256) void ffn2_fb_k(
    const bf16_t* __restrict__ h, const float* __restrict__ w2, const float* __restrict__ b2,
    const float* __restrict__ sc_tmp, const int* __restrict__ counts,
    const int* __restrict__ offsets, float* __restrict__ rowv)
{
    int e  = blockIdx.x >> 5;
    int mt = blockIdx.x & 31;
    int nt = blockIdx.y;
    int ne = counts[e];
    if (mt * BM >= ne) return;
    int nb = nt * BN;
    int off = offsets[e];
    const float* W = w2 + (size_t)e * F_DIM * D_DIM;

    __shared__ alignas(16) char smem[SMEM_BYTES];
    bf16_t* As = (bf16_t*)smem;
    bf16_t* Bs = (bf16_t*)(smem + 10240);
    float* rowsc = (float*)(smem + 34816);

    int tid = threadIdx.x;
    if (tid < 128) {
        int r = mt*BM + tid;
        rowsc[tid] = (r < ne) ? sc_tmp[e*T_TOK + r] : 0.0f;
    }
    __syncthreads();

    f32x4 acc[4][4] = {};
    int wave = tid >> 6, lane = tid & 63;
    int wm = (wave & 1) * 64, wnn = wave >> 1;
    int fr = lane & 15, fk = (lane >> 4) * 8;
    int sr = tid >> 1, sh = (tid & 1) * 16;
    int bn_ = tid & 127, bk_ = (tid >> 7) * 16;
    bool arow_valid = (mt*BM + sr) < ne;
    const bf16_t* asrc0 = h + (size_t)(off + mt*BM + sr) * F_DIM + sh;

    for (int k0 = 0; k0 < F_DIM; k0 += BK) {
        {
            bf16x8 v0, v1;
            if (arow_valid) {
                v0 = *(const bf16x8*)(asrc0 + k0);
                v1 = *(const bf16x8*)(asrc0 + k0 + 8);
            } else {
                v0 = (bf16x8)(bf16_t)0.0f; v1 = (bf16x8)(bf16_t)0.0f;
            }
            *(bf16x8*)(As + sr*LDA + sh)     = v0;
            *(bf16x8*)(As + sr*LDA + sh + 8) = v1;
        }
        {
            union { bf16_t u[16]; bf16x8 v[2]; } pk;
            const float* src = W + (size_t)(k0 + bk_) * D_DIM + nb + bn_;
#pragma unroll
            for (int j = 0; j < 16; j++) pk.u[j] = (bf16_t)src[(size_t)j * D_DIM];
            *(bf16x8*)(Bs + bn_*LDA + bk_)     = pk.v[0];
            *(bf16x8*)(Bs + bn_*LDA + bk_ + 8) = pk.v[1];
        }
        __syncthreads();
        bf16x8 af[4], bfr[4];
#pragma unroll
        for (int i = 0; i < 4; i++) af[i]  = *(bf16x8*)(As + (wm + i*16 + fr)*LDA + fk);
#pragma unroll
        for (int i = 0; i < 4; i++) bfr[i] = *(bf16x8*)(Bs + (wnn*64 + i*16 + fr)*LDA + fk);
#pragma unroll
        for (int mi = 0; mi < 4; mi++)
#pragma unroll
            for (int ni = 0; ni < 4; ni++)
                acc[mi][ni] = __builtin_amdgcn_mfma_f32_16x16x32_bf16(af[mi], bfr[ni], acc[mi][ni], 0, 0, 0);
        __syncthreads();
    }

    const float* b2e = b2 + (size_t)e * D_DIM + nb;
    float* Ctf = (float*)smem;
    for (int half = 0; half < 2; half++) {
        if (wnn == half) {
#pragma unroll
            for (int mi = 0; mi < 4; mi++) {
                int row = wm + mi*16 + ((lane >> 4) << 2);
#pragma unroll
                for (int ni = 0; ni < 4; ni++) {
                    int lcol = ni*16 + fr;
                    float bb = b2e[half*64 + lcol];
#pragma unroll
                    for (int r = 0; r < 4; r++) {
                        float v = (acc[mi][ni][r] + bb) * rowsc[row + r];
                        Ctf[(row + r)*LDCF + lcol] = v;
                    }
                }
            }
        }
        __syncthreads();
        {
            int row = tid >> 1, seg = (tid & 1) * 32;
            if (mt*BM + row < ne) {
                float* dst = rowv + (size_t)(off + mt*BM + row) * D_DIM + nb + half*64 + seg;
#pragma unroll
                for (int j = 0; j < 8; j++)
                    *(f32x4*)(dst + j*4) = *(f32x4*)(Ctf + row*LDCF + seg + j*4);
            }
        }
        __syncthreads();
    }
}

__global__ __launch_bounds__(256) void combine_fb_k(
    const float* __restrict__ rowv, const int* __restrict__ tok2row,
    const int* __restrict__ offsets, float* __restrict__ out)
{
    int t = blockIdx.x;
    int p0 = tok2row[t*2], p1 = tok2row[t*2+1];
    int r0 = offsets[p0 >> 16] + (p0 & 0xffff);
    int r1 = offsets[p1 >> 16] + (p1 & 0xffff);
    int d = threadIdx.x * 4;
    f32x4 a = *(const f32x4*)(rowv + (size_t)r0 * D_DIM + d);
    f32x4 b = *(const f32x4*)(rowv + (size_t)r1 * D_DIM + d);
    *(f32x4*)(out + (size_t)t * D_DIM + d) = a + b;
}

// ======================= launch =======================
extern "C" void kernel_launch(void* const* d_in, const int* in_sizes, int n_in,
                              void* d_out, int out_size, void* d_ws, size_t ws_size,
                              hipStream_t stream) {
    const float* x       = (const float*)d_in[0];
    const float* noise   = (const float*)d_in[1];
    const float* gate_w  = (const float*)d_in[2];
    const float* gate_b  = (const float*)d_in[3];
    const float* noise_w = (const float*)d_in[4];
    const float* noise_b = (const float*)d_in[5];
    const float* w1      = (const float*)d_in[6];
    const float* b1      = (const float*)d_in[7];
    const float* w2      = (const float*)d_in[8];
    const float* b2      = (const float*)d_in[9];
    float* out = (float*)d_out;
    char* ws = (char*)d_ws;

    if (ws_size >= FAST_NEED) {
        bf16_t* w1t     = (bf16_t*)(ws + F_W1T);
        bf16_t* w2t     = (bf16_t*)(ws + F_W2T);
        char*   h_t     = ws + F_HT;
        bf16_t* xb      = (bf16_t*)(ws + F_XBF);
        bf16_t* rowv    = (bf16_t*)(ws + F_ROWV);
        float*  scores  = (float*) (ws + F_SCORES);
        int*    tok_tmp = (int*)   (ws + F_TOK);
        float*  sc_tmp  = (float*) (ws + F_SC);
        int*    tok2row = (int*)   (ws + F_T2R);
        int*    counts  = (int*)   (ws + F_CNT);
        int*    offsets = (int*)   (ws + F_OFF);
        int*    blk_off = (int*)   (ws + F_BLK);

        hipMemsetAsync(ws + F_CNT, 0, 32, stream);
        mega_prep_k<<<11264, 256, 0, stream>>>(x, noise, gate_w, gate_b, noise_w, noise_b,
                                               w1, w2, w1t, w2t, xb,
                                               scores, tok_tmp, sc_tmp, tok2row, counts);
        prefix_k<<<1, 64, 0, stream>>>(counts, offsets, blk_off);
        aux_k<<<1, 256, 0, stream>>>(scores, out + (size_t)T_TOK * D_DIM);
        ffn1_v3_k<<<8192, 256, 0, stream>>>(xb, w1t, b1, tok_tmp, counts, blk_off, h_t);
        ffn2_v3_k<<<2048, 256, 0, stream>>>(h_t, w2t, b2, sc_tmp, counts, offsets, blk_off, rowv);
        combine_v3_k<<<T_TOK, 256, 0, stream>>>(rowv, tok2row, offsets, out);
    } else {
        bf16_t* h       = (bf16_t*)(ws + WS_H);
        float*  rowv    = (float*) (ws + WS_ROWV);
        float*  scores  = (float*) (ws + WS_SCORES);
        int*    tok_tmp = (int*)   (ws + WS_TOK);
        float*  sc_tmp  = (float*) (ws + WS_SC);
        int*    tok2row = (int*)   (ws + WS_T2R);
        int*    counts  = (int*)   (ws + WS_CNT);
        int*    offsets = (int*)   (ws + WS_OFF);

        hipMemsetAsync(ws + WS_CNT, 0, 32, stream);
        router_fb_k<<<T_TOK/4, 256, 0, stream>>>(x, noise, gate_w, gate_b, noise_w, noise_b,
                                                 scores, tok_tmp, sc_tmp, tok2row, counts);
        prefix_k<<<1, 64, 0, stream>>>(counts, offsets, (int*)(ws + WS_BLK));
        aux_k<<<1, 256, 0, stream>>>(scores, out + (size_t)T_TOK * D_DIM);
        ffn1_fb_k<<<dim3(E_NUM*32, F_DIM/BN), 256, 0, stream>>>(x, w1, b1, tok_tmp, counts, offsets, h);
        ffn2_fb_k<<<dim3(E_NUM*32, D_DIM/BN), 256, 0, stream>>>(h, w2, b2, sc_tmp, counts, offsets, rowv);
        combine_fb_k<<<T_TOK, 256, 0, stream>>>(rowv, tok2row, offsets, out);
    }
}